// Round 1
// baseline (721.340 us; speedup 1.0000x reference)
//
#include <hip/hip_runtime.h>
#include <hip/hip_bf16.h>
#include <math.h>

#define DIM   2048
#define NH    16
#define HD    128
#define SEQ   2048
#define BATCH 2
#define QKVN  6144   // 3*DIM

typedef __attribute__((ext_vector_type(8))) short short8;
typedef __attribute__((ext_vector_type(4))) float f32x4;
typedef __attribute__((ext_vector_type(4))) unsigned int u32x4;

static __device__ __forceinline__ unsigned short f2bf(float f) {
    __hip_bfloat16 h = __float2bfloat16(f);
    return *reinterpret_cast<unsigned short*>(&h);
}

// ---------------- cast fp32 -> bf16 ----------------
__global__ void cast_kernel(const float* __restrict__ in, __hip_bfloat16* __restrict__ out, int n) {
    int i = (blockIdx.x * blockDim.x + threadIdx.x) * 4;
    if (i >= n) return;
    float4 v = *(const float4*)(in + i);
    union { unsigned short u[4]; uint2 d; } pk;
    pk.u[0] = f2bf(v.x); pk.u[1] = f2bf(v.y); pk.u[2] = f2bf(v.z); pk.u[3] = f2bf(v.w);
    *(uint2*)(out + i) = pk.d;
}

// ---------------- RoPE (in-place on Q,K sections of QKV) ----------------
__global__ void rope_kernel(__hip_bfloat16* __restrict__ qkv) {
    int idx = blockIdx.x * blockDim.x + threadIdx.x;   // 4096*16*64 threads
    int m    = idx >> 10;          // row in [0,4096)
    int rest = idx & 1023;
    int h    = rest >> 6;          // head
    int i    = rest & 63;          // pair index
    int s    = m & (SEQ - 1);      // position
    float theta = __expf(-((float)(2 * i) * (1.0f / (float)HD)) * 9.210340371976184f); // ln(10000)
    float ang = (float)s * theta;
    float sn, cs;
    sincosf(ang, &sn, &cs);
    size_t base = (size_t)m * QKVN + h * HD + 2 * i;
    float q0 = __bfloat162float(qkv[base]);
    float q1 = __bfloat162float(qkv[base + 1]);
    qkv[base]     = __float2bfloat16(q0 * cs - q1 * sn);
    qkv[base + 1] = __float2bfloat16(q1 * cs + q0 * sn);
    float k0 = __bfloat162float(qkv[base + DIM]);
    float k1 = __bfloat162float(qkv[base + DIM + 1]);
    qkv[base + DIM]     = __float2bfloat16(k0 * cs - k1 * sn);
    qkv[base + DIM + 1] = __float2bfloat16(k1 * cs + k0 * sn);
}

// ---------------- bf16 GEMM, C[m,n] = sum_k A[m,k]*B[n,k] ----------------
__device__ __forceinline__ void storeC(float* C, size_t idx, float v) { C[idx] = v; }
__device__ __forceinline__ void storeC(__hip_bfloat16* C, size_t idx, float v) { C[idx] = __float2bfloat16(v); }

template <typename OutT>
__global__ __launch_bounds__(256) void gemm_bt(const __hip_bfloat16* __restrict__ A,
                                               const __hip_bfloat16* __restrict__ B,
                                               OutT* __restrict__ C, int M, int N, int K) {
    constexpr int BM = 128, BN = 128, BK = 64, LDAB = BK + 8;  // pad +8 bf16: 2-way conflicts only
    __shared__ __align__(16) __hip_bfloat16 As[BM * LDAB];
    __shared__ __align__(16) __hip_bfloat16 Bs[BN * LDAB];
    int tid  = threadIdx.x;
    int lane = tid & 63;
    int wave = tid >> 6;
    int quad = lane >> 4;
    int l15  = lane & 15;
    int wr   = wave >> 1, wc = wave & 1;
    int m0 = blockIdx.y * BM;
    int n0 = blockIdx.x * BN;
    f32x4 acc[4][4] = {};
    int srow = tid >> 3;         // 0..31
    int scol = (tid & 7) * 8;    // 0,8,..,56

    for (int k0 = 0; k0 < K; k0 += BK) {
        __syncthreads();
#pragma unroll
        for (int i = 0; i < 4; i++) {
            int r = srow + i * 32;
            u32x4 av = *(const u32x4*)(A + (size_t)(m0 + r) * K + k0 + scol);
            u32x4 bv = *(const u32x4*)(B + (size_t)(n0 + r) * K + k0 + scol);
            *(u32x4*)(As + r * LDAB + scol) = av;
            *(u32x4*)(Bs + r * LDAB + scol) = bv;
        }
        __syncthreads();
#pragma unroll
        for (int kk = 0; kk < BK; kk += 32) {
            short8 af[4], bf[4];
#pragma unroll
            for (int t = 0; t < 4; t++) {
                af[t] = *(const short8*)(As + (wr * 64 + t * 16 + l15) * LDAB + kk + quad * 8);
                bf[t] = *(const short8*)(Bs + (wc * 64 + t * 16 + l15) * LDAB + kk + quad * 8);
            }
#pragma unroll
            for (int mt = 0; mt < 4; mt++)
#pragma unroll
                for (int nt = 0; nt < 4; nt++)
                    acc[mt][nt] = __builtin_amdgcn_mfma_f32_16x16x32_bf16(af[mt], bf[nt], acc[mt][nt], 0, 0, 0);
        }
    }
#pragma unroll
    for (int mt = 0; mt < 4; mt++)
#pragma unroll
        for (int nt = 0; nt < 4; nt++)
#pragma unroll
            for (int r = 0; r < 4; r++) {
                int row = m0 + wr * 64 + mt * 16 + quad * 4 + r;
                int col = n0 + wc * 64 + nt * 16 + l15;
                storeC(C, (size_t)row * N + col, acc[mt][nt][r]);
            }
}

// ---------------- flash attention (causal) ----------------
// grid: (S/64 qtiles, B*NH). block 256 = 4 waves; wave w owns q rows [qt*64+w*16, +16)
__global__ __launch_bounds__(256) void flash_kernel(const __hip_bfloat16* __restrict__ qkv,
                                                    __hip_bfloat16* __restrict__ attn) {
    constexpr int LDK = HD + 8;   // 136
    constexpr int LDV = 64 + 8;   // 72
    __shared__ __align__(16) __hip_bfloat16 Ks[64 * LDK];
    __shared__ __align__(16) __hip_bfloat16 Vt[HD * LDV];
    __shared__ __align__(16) __hip_bfloat16 Ps[4 * 16 * LDV];
    int tid  = threadIdx.x;
    int lane = tid & 63;
    int wave = tid >> 6;
    int quad = lane >> 4;
    int l15  = lane & 15;
    int qt = blockIdx.x;
    int bh = blockIdx.y;
    int b  = bh >> 4;
    int h  = bh & 15;
    size_t row0 = (size_t)b * SEQ;

    // Q fragments (A-operand layout): qf[c][j] = Q[q=l15-row][d=c*32+quad*8+j]
    short8 qf[4];
    {
        int qrow = qt * 64 + wave * 16 + l15;
        const __hip_bfloat16* qptr = qkv + (row0 + qrow) * (size_t)QKVN + h * HD + quad * 8;
#pragma unroll
        for (int c = 0; c < 4; c++) qf[c] = *(const short8*)(qptr + c * 32);
    }

    f32x4 o[8] = {};
    float mprev[4] = {-INFINITY, -INFINITY, -INFINITY, -INFINITY};
    float lsum[4]  = {0.f, 0.f, 0.f, 0.f};
    const float scale = 0.08838834764831845f;   // 1/sqrt(128)

    for (int kt = 0; kt <= qt; kt++) {
        __syncthreads();
        // stage K tile [64][128] and V^T tile [128][64]
#pragma unroll
        for (int i = 0; i < 4; i++) {
            int chunk = tid + 256 * i;        // 0..1023
            int r  = chunk >> 4;              // key row 0..63
            int cc = chunk & 15;              // 8-elem chunk of d
            const __hip_bfloat16* kp = qkv + (row0 + kt * 64 + r) * (size_t)QKVN + DIM + h * HD + cc * 8;
            u32x4 kv = *(const u32x4*)kp;
            *(u32x4*)(Ks + r * LDK + cc * 8) = kv;
            u32x4 vv = *(const u32x4*)(kp + DIM);
            __hip_bfloat16 tmp[8];
            *(u32x4*)tmp = vv;
#pragma unroll
            for (int j = 0; j < 8; j++) Vt[(cc * 8 + j) * LDV + r] = tmp[j];
        }
        __syncthreads();

        // S = Q K^T  (s[nt][r]: q-row = quad*4+r, key-col = nt*16+l15)
        f32x4 s[4];
#pragma unroll
        for (int nt = 0; nt < 4; nt++) {
            f32x4 a = {};
#pragma unroll
            for (int c = 0; c < 4; c++) {
                short8 kf = *(const short8*)(Ks + (nt * 16 + l15) * LDK + c * 32 + quad * 8);
                a = __builtin_amdgcn_mfma_f32_16x16x32_bf16(qf[c], kf, a, 0, 0, 0);
            }
            s[nt] = a;
        }
        bool diag = (kt == qt);
#pragma unroll
        for (int nt = 0; nt < 4; nt++) {
            int key = kt * 64 + nt * 16 + l15;
#pragma unroll
            for (int r = 0; r < 4; r++) {
                float v = s[nt][r] * scale;
                if (diag) {
                    int q = qt * 64 + wave * 16 + quad * 4 + r;
                    if (key > q) v = -INFINITY;
                }
                s[nt][r] = v;
            }
        }
        // online softmax
        float alpha[4];
#pragma unroll
        for (int r = 0; r < 4; r++) {
            float v = fmaxf(fmaxf(s[0][r], s[1][r]), fmaxf(s[2][r], s[3][r]));
            v = fmaxf(v, __shfl_xor(v, 1));
            v = fmaxf(v, __shfl_xor(v, 2));
            v = fmaxf(v, __shfl_xor(v, 4));
            v = fmaxf(v, __shfl_xor(v, 8));
            float mnew = fmaxf(mprev[r], v);
            alpha[r] = __expf(mprev[r] - mnew);
            mprev[r] = mnew;
        }
#pragma unroll
        for (int r = 0; r < 4; r++) {
            float sum = 0.f;
#pragma unroll
            for (int nt = 0; nt < 4; nt++) {
                float p = __expf(s[nt][r] - mprev[r]);
                s[nt][r] = p;
                sum += p;
            }
            sum += __shfl_xor(sum, 1);
            sum += __shfl_xor(sum, 2);
            sum += __shfl_xor(sum, 4);
            sum += __shfl_xor(sum, 8);
            lsum[r] = lsum[r] * alpha[r] + sum;
        }
        // P (C-layout) -> LDS -> A-layout
        __hip_bfloat16* pw = Ps + wave * 16 * LDV;
#pragma unroll
        for (int nt = 0; nt < 4; nt++)
#pragma unroll
            for (int r = 0; r < 4; r++)
                pw[(quad * 4 + r) * LDV + nt * 16 + l15] = __float2bfloat16(s[nt][r]);
        __syncthreads();
#pragma unroll
        for (int dt = 0; dt < 8; dt++)
#pragma unroll
            for (int r = 0; r < 4; r++) o[dt][r] *= alpha[r];
        short8 pf0 = *(const short8*)(pw + l15 * LDV + quad * 8);
        short8 pf1 = *(const short8*)(pw + l15 * LDV + 32 + quad * 8);
#pragma unroll
        for (int dt = 0; dt < 8; dt++) {
            short8 vf0 = *(const short8*)(Vt + (dt * 16 + l15) * LDV + quad * 8);
            short8 vf1 = *(const short8*)(Vt + (dt * 16 + l15) * LDV + 32 + quad * 8);
            o[dt] = __builtin_amdgcn_mfma_f32_16x16x32_bf16(pf0, vf0, o[dt], 0, 0, 0);
            o[dt] = __builtin_amdgcn_mfma_f32_16x16x32_bf16(pf1, vf1, o[dt], 0, 0, 0);
        }
    }
    // finalize: O /= l, store bf16 into attn [4096][2048]
    int qbase = qt * 64 + wave * 16 + quad * 4;
#pragma unroll
    for (int r = 0; r < 4; r++) {
        float inv = 1.0f / lsum[r];
#pragma unroll
        for (int dt = 0; dt < 8; dt++) {
            attn[(row0 + qbase + r) * (size_t)DIM + h * HD + dt * 16 + l15] =
                __float2bfloat16(o[dt][r] * inv);
        }
    }
}

extern "C" void kernel_launch(void* const* d_in, const int* in_sizes, int n_in,
                              void* d_out, int out_size, void* d_ws, size_t ws_size,
                              hipStream_t stream) {
    const float* x  = (const float*)d_in[0];
    // d_in[1] = mask (unused; causal mask applied analytically)
    const float* wq = (const float*)d_in[2];
    const float* wk = (const float*)d_in[3];
    const float* wv = (const float*)d_in[4];
    const float* wo = (const float*)d_in[5];
    float* out = (float*)d_out;

    char* ws = (char*)d_ws;
    __hip_bfloat16* xb    = (__hip_bfloat16*)(ws);                 // 4096x2048
    __hip_bfloat16* wqkvb = (__hip_bfloat16*)(ws + 16777216ull);   // 6144x2048
    __hip_bfloat16* wob   = (__hip_bfloat16*)(ws + 41943040ull);   // 2048x2048
    __hip_bfloat16* qkv   = (__hip_bfloat16*)(ws + 50331648ull);   // 4096x6144
    __hip_bfloat16* attn  = (__hip_bfloat16*)(ws + 100663296ull);  // 4096x2048

    const int nx = BATCH * SEQ * DIM;    // 8388608
    const int nw = DIM * DIM;            // 4194304
    cast_kernel<<<nx / 4 / 256, 256, 0, stream>>>(x, xb, nx);
    cast_kernel<<<nw / 4 / 256, 256, 0, stream>>>(wq, wqkvb, nw);
    cast_kernel<<<nw / 4 / 256, 256, 0, stream>>>(wk, wqkvb + (size_t)DIM * DIM, nw);
    cast_kernel<<<nw / 4 / 256, 256, 0, stream>>>(wv, wqkvb + 2ull * DIM * DIM, nw);
    cast_kernel<<<nw / 4 / 256, 256, 0, stream>>>(wo, wob, nw);

    // QKV = xb @ wqkvb^T : M=4096, N=6144, K=2048
    gemm_bt<__hip_bfloat16><<<dim3(QKVN / 128, (BATCH * SEQ) / 128), 256, 0, stream>>>(
        xb, wqkvb, qkv, BATCH * SEQ, QKVN, DIM);

    rope_kernel<<<(BATCH * SEQ * NH * (HD / 2)) / 256, 256, 0, stream>>>(qkv);

    flash_kernel<<<dim3(SEQ / 64, BATCH * NH), 256, 0, stream>>>(qkv, attn);

    // out = attn @ wo^T : M=4096, N=2048, K=2048 (fp32 out)
    gemm_bt<float><<<dim3(DIM / 128, (BATCH * SEQ) / 128), 256, 0, stream>>>(
        attn, wob, out, BATCH * SEQ, DIM, DIM);
}

// Round 2
// 433.284 us; speedup vs baseline: 1.6648x; 1.6648x over previous
//
#include <hip/hip_runtime.h>
#include <hip/hip_bf16.h>
#include <math.h>

#define DIM   2048
#define NH    16
#define HD    128
#define SEQ   2048
#define BATCH 2
#define QKVN  6144   // 3*DIM

typedef __attribute__((ext_vector_type(8))) short short8;
typedef __attribute__((ext_vector_type(4))) float f32x4;
typedef __attribute__((ext_vector_type(4))) unsigned int u32x4;

static __device__ __forceinline__ unsigned short f2bf(float f) {
    __hip_bfloat16 h = __float2bfloat16(f);
    return *reinterpret_cast<unsigned short*>(&h);
}

// async global->LDS, 16B per lane; LDS dest = base + lane*16 (wave-uniform base)
static __device__ __forceinline__ void gload16(const __hip_bfloat16* g, __hip_bfloat16* l) {
    __builtin_amdgcn_global_load_lds(
        (__attribute__((address_space(1))) void*)(g),
        (__attribute__((address_space(3))) void*)(l), 16, 0, 0);
}

// ---------------- cast fp32 -> bf16 ----------------
__global__ void cast_kernel(const float* __restrict__ in, __hip_bfloat16* __restrict__ out, int n) {
    int i = (blockIdx.x * blockDim.x + threadIdx.x) * 4;
    if (i >= n) return;
    float4 v = *(const float4*)(in + i);
    union { unsigned short u[4]; uint2 d; } pk;
    pk.u[0] = f2bf(v.x); pk.u[1] = f2bf(v.y); pk.u[2] = f2bf(v.z); pk.u[3] = f2bf(v.w);
    *(uint2*)(out + i) = pk.d;
}

// ---------------- RoPE (in-place on Q,K sections of QKV) ----------------
__global__ void rope_kernel(__hip_bfloat16* __restrict__ qkv) {
    int idx = blockIdx.x * blockDim.x + threadIdx.x;
    int m    = idx >> 10;          // row in [0,4096)
    int rest = idx & 1023;
    int h    = rest >> 6;          // head
    int i    = rest & 63;          // pair index
    int s    = m & (SEQ - 1);      // position
    float theta = __expf(-((float)(2 * i) * (1.0f / (float)HD)) * 9.210340371976184f);
    float ang = (float)s * theta;
    float sn, cs;
    sincosf(ang, &sn, &cs);
    size_t base = (size_t)m * QKVN + h * HD + 2 * i;
    float q0 = __bfloat162float(qkv[base]);
    float q1 = __bfloat162float(qkv[base + 1]);
    qkv[base]     = __float2bfloat16(q0 * cs - q1 * sn);
    qkv[base + 1] = __float2bfloat16(q1 * cs + q0 * sn);
    float k0 = __bfloat162float(qkv[base + DIM]);
    float k1 = __bfloat162float(qkv[base + DIM + 1]);
    qkv[base + DIM]     = __float2bfloat16(k0 * cs - k1 * sn);
    qkv[base + DIM + 1] = __float2bfloat16(k1 * cs + k0 * sn);
}

// ---------------- V transpose: qkv V section -> Vt[bh][d][s] ----------------
__global__ __launch_bounds__(256) void vtrans_kernel(const __hip_bfloat16* __restrict__ qkv,
                                                     __hip_bfloat16* __restrict__ vt) {
    __shared__ __align__(16) __hip_bfloat16 T[64 * 64];
    int tid = threadIdx.x;
    int s0 = blockIdx.x * 64;
    int d0 = blockIdx.y * 64;
    int b  = blockIdx.z;
#pragma unroll
    for (int i = 0; i < 2; i++) {
        int ch = tid + 256 * i;
        int r  = ch >> 3;          // s row 0..63
        int cc = ch & 7;           // d chunk
        u32x4 v = *(const u32x4*)(qkv + ((size_t)(b * SEQ + s0 + r)) * QKVN + 2 * DIM + d0 + cc * 8);
        __hip_bfloat16 tmp[8];
        *(u32x4*)tmp = v;
#pragma unroll
        for (int j = 0; j < 8; j++) {
            int dl = cc * 8 + j;
            int chunk = ((r >> 3) ^ (dl & 7) ^ (dl >> 3)) & 7;   // XOR swizzle: write conflict-free
            T[dl * 64 + chunk * 8 + (r & 7)] = tmp[j];
        }
    }
    __syncthreads();
#pragma unroll
    for (int i = 0; i < 2; i++) {
        int ch = tid + 256 * i;
        int dl = ch >> 3;          // d row 0..63
        int sc = ch & 7;           // s chunk
        int chunk = (sc ^ (dl & 7) ^ (dl >> 3)) & 7;
        u32x4 v = *(const u32x4*)(T + dl * 64 + chunk * 8);
        int d = d0 + dl;
        int h = d >> 7, dd = d & 127;
        *(u32x4*)(vt + ((size_t)((b * NH + h) * HD + dd)) * SEQ + s0 + sc * 8) = v;
    }
}

// ---------------- bf16 GEMM, C[m,n] = sum_k A[m,k]*B[n,k] ----------------
__device__ __forceinline__ void storeC(float* C, size_t idx, float v) { C[idx] = v; }
__device__ __forceinline__ void storeC(__hip_bfloat16* C, size_t idx, float v) { C[idx] = __float2bfloat16(v); }

template <typename OutT>
__global__ __launch_bounds__(256) void gemm_bt(const __hip_bfloat16* __restrict__ A,
                                               const __hip_bfloat16* __restrict__ B,
                                               OutT* __restrict__ C, int M, int N, int K) {
    constexpr int BK = 64;
    __shared__ __align__(16) __hip_bfloat16 As[128 * BK];   // unpadded, chunk-swizzled
    __shared__ __align__(16) __hip_bfloat16 Bs[128 * BK];
    int tid  = threadIdx.x;
    int lane = tid & 63;
    int wave = tid >> 6;
    int quad = lane >> 4;
    int l15  = lane & 15;
    int wr   = wave >> 1, wc = wave & 1;
    int m0 = blockIdx.y * 128;
    int n0 = blockIdx.x * 128;
    f32x4 acc[4][4] = {};

    for (int k0 = 0; k0 < K; k0 += BK) {
        __syncthreads();
#pragma unroll
        for (int c = 0; c < 4; c++) {
            int br = (wave * 4 + c) * 8;      // 8 rows per wave-call
            int r  = br + (lane >> 3);
            int cc = (lane & 7) ^ (r & 7);    // swizzled source chunk
            gload16(A + (size_t)(m0 + r) * K + k0 + cc * 8, As + br * 64);
            gload16(B + (size_t)(n0 + r) * K + k0 + cc * 8, Bs + br * 64);
        }
        __syncthreads();
#pragma unroll
        for (int kk = 0; kk < BK; kk += 32) {
            short8 af[4], bf4[4];
#pragma unroll
            for (int t = 0; t < 4; t++) {
                int Ra = wr * 64 + t * 16 + l15;
                int pa = ((kk >> 3) + quad) ^ (Ra & 7);
                af[t] = *(const short8*)(As + Ra * 64 + pa * 8);
                int Rb = wc * 64 + t * 16 + l15;
                int pb = ((kk >> 3) + quad) ^ (Rb & 7);
                bf4[t] = *(const short8*)(Bs + Rb * 64 + pb * 8);
            }
#pragma unroll
            for (int mt = 0; mt < 4; mt++)
#pragma unroll
                for (int nt = 0; nt < 4; nt++)
                    acc[mt][nt] = __builtin_amdgcn_mfma_f32_16x16x32_bf16(af[mt], bf4[nt], acc[mt][nt], 0, 0, 0);
        }
    }
#pragma unroll
    for (int mt = 0; mt < 4; mt++)
#pragma unroll
        for (int nt = 0; nt < 4; nt++)
#pragma unroll
            for (int r = 0; r < 4; r++) {
                int row = m0 + wr * 64 + mt * 16 + quad * 4 + r;
                int col = n0 + wc * 64 + nt * 16 + l15;
                storeC(C, (size_t)row * N + col, acc[mt][nt][r]);
            }
}

// ---------------- flash attention (causal, qtile-paired for load balance) ----------------
// grid: (16 pairs, B*NH). block 256 = 4 waves; wave w owns q rows [qt*64+w*16, +16)
__global__ __launch_bounds__(256) void flash_kernel(const __hip_bfloat16* __restrict__ qkv,
                                                    const __hip_bfloat16* __restrict__ vt,
                                                    __hip_bfloat16* __restrict__ attn) {
    __shared__ __align__(16) __hip_bfloat16 Ks[64 * 128];    // swizzled chunks of 8
    __shared__ __align__(16) __hip_bfloat16 Vts[128 * 64];   // Vt rows, swizzled
    constexpr int LDP = 72;
    __shared__ __align__(16) __hip_bfloat16 Ps[4 * 16 * LDP];
    int tid  = threadIdx.x;
    int lane = tid & 63;
    int wave = tid >> 6;
    int quad = lane >> 4;
    int l15  = lane & 15;
    int pairi = blockIdx.x;      // 0..15
    int bh = blockIdx.y;
    int b  = bh >> 4;
    int h  = bh & 15;
    size_t row0 = (size_t)b * SEQ;
    const __hip_bfloat16* vbase = vt + (size_t)bh * HD * SEQ;
    const float scale = 0.08838834764831845f;   // 1/sqrt(128)

    for (int seg = 0; seg < 2; seg++) {
        int qt = seg ? (31 - pairi) : pairi;
        short8 qf[4];
        {
            int qrow = qt * 64 + wave * 16 + l15;
            const __hip_bfloat16* qptr = qkv + (row0 + qrow) * (size_t)QKVN + h * HD + quad * 8;
#pragma unroll
            for (int c = 0; c < 4; c++) qf[c] = *(const short8*)(qptr + c * 32);
        }
        f32x4 o[8] = {};
        float mprev[4] = {-INFINITY, -INFINITY, -INFINITY, -INFINITY};
        float lsum[4]  = {0.f, 0.f, 0.f, 0.f};

        for (int kt = 0; kt <= qt; kt++) {
            __syncthreads();
            // stage K tile [64][128]: 16 wave-calls of 1KB (4 rows each)
#pragma unroll
            for (int c = 0; c < 4; c++) {
                int br = (wave * 4 + c) * 4;
                int r  = br + (lane >> 4);
                int cc = (lane & 15) ^ (r & 15);
                gload16(qkv + (row0 + kt * 64 + r) * (size_t)QKVN + DIM + h * HD + cc * 8,
                        Ks + br * 128);
            }
            // stage Vt tile [128][64]: 16 wave-calls (8 rows each)
#pragma unroll
            for (int c = 0; c < 4; c++) {
                int br = (wave * 4 + c) * 8;
                int r  = br + (lane >> 3);
                int cc = (lane & 7) ^ (r & 7);
                gload16(vbase + (size_t)r * SEQ + kt * 64 + cc * 8, Vts + br * 64);
            }
            __syncthreads();

            // S = Q K^T
            f32x4 s[4];
#pragma unroll
            for (int nt = 0; nt < 4; nt++) {
                f32x4 a = {};
                int R = nt * 16 + l15;
#pragma unroll
                for (int c = 0; c < 4; c++) {
                    int phys = (c * 4 + quad) ^ (R & 15);
                    short8 kf = *(const short8*)(Ks + R * 128 + phys * 8);
                    a = __builtin_amdgcn_mfma_f32_16x16x32_bf16(qf[c], kf, a, 0, 0, 0);
                }
                s[nt] = a;
            }
            bool diag = (kt == qt);
#pragma unroll
            for (int nt = 0; nt < 4; nt++) {
                int key = kt * 64 + nt * 16 + l15;
#pragma unroll
                for (int r = 0; r < 4; r++) {
                    float v = s[nt][r] * scale;
                    if (diag) {
                        int q = qt * 64 + wave * 16 + quad * 4 + r;
                        if (key > q) v = -INFINITY;
                    }
                    s[nt][r] = v;
                }
            }
            float alpha[4];
#pragma unroll
            for (int r = 0; r < 4; r++) {
                float v = fmaxf(fmaxf(s[0][r], s[1][r]), fmaxf(s[2][r], s[3][r]));
                v = fmaxf(v, __shfl_xor(v, 1));
                v = fmaxf(v, __shfl_xor(v, 2));
                v = fmaxf(v, __shfl_xor(v, 4));
                v = fmaxf(v, __shfl_xor(v, 8));
                float mnew = fmaxf(mprev[r], v);
                alpha[r] = __expf(mprev[r] - mnew);
                mprev[r] = mnew;
            }
#pragma unroll
            for (int r = 0; r < 4; r++) {
                float sum = 0.f;
#pragma unroll
                for (int nt = 0; nt < 4; nt++) {
                    float p = __expf(s[nt][r] - mprev[r]);
                    s[nt][r] = p;
                    sum += p;
                }
                sum += __shfl_xor(sum, 1);
                sum += __shfl_xor(sum, 2);
                sum += __shfl_xor(sum, 4);
                sum += __shfl_xor(sum, 8);
                lsum[r] = lsum[r] * alpha[r] + sum;
            }
            // P (C-layout) -> LDS -> A-layout. Ps region is wave-private: no barrier needed.
            __hip_bfloat16* pw = Ps + wave * 16 * LDP;
#pragma unroll
            for (int nt = 0; nt < 4; nt++)
#pragma unroll
                for (int r = 0; r < 4; r++)
                    pw[(quad * 4 + r) * LDP + nt * 16 + l15] = __float2bfloat16(s[nt][r]);
#pragma unroll
            for (int dt = 0; dt < 8; dt++)
#pragma unroll
                for (int r = 0; r < 4; r++) o[dt][r] *= alpha[r];
            short8 pf0 = *(const short8*)(pw + l15 * LDP + quad * 8);
            short8 pf1 = *(const short8*)(pw + l15 * LDP + 32 + quad * 8);
#pragma unroll
            for (int dt = 0; dt < 8; dt++) {
                int d = dt * 16 + l15;
                int p0 = (0 + quad) ^ (d & 7);
                int p1 = (4 + quad) ^ (d & 7);
                short8 vf0 = *(const short8*)(Vts + d * 64 + p0 * 8);
                short8 vf1 = *(const short8*)(Vts + d * 64 + p1 * 8);
                o[dt] = __builtin_amdgcn_mfma_f32_16x16x32_bf16(pf0, vf0, o[dt], 0, 0, 0);
                o[dt] = __builtin_amdgcn_mfma_f32_16x16x32_bf16(pf1, vf1, o[dt], 0, 0, 0);
            }
        }
        int qbase = qt * 64 + wave * 16 + quad * 4;
#pragma unroll
        for (int r = 0; r < 4; r++) {
            float inv = 1.0f / lsum[r];
#pragma unroll
            for (int dt = 0; dt < 8; dt++) {
                attn[(row0 + qbase + r) * (size_t)DIM + h * HD + dt * 16 + l15] =
                    __float2bfloat16(o[dt][r] * inv);
            }
        }
    }
}

extern "C" void kernel_launch(void* const* d_in, const int* in_sizes, int n_in,
                              void* d_out, int out_size, void* d_ws, size_t ws_size,
                              hipStream_t stream) {
    const float* x  = (const float*)d_in[0];
    const float* wq = (const float*)d_in[2];
    const float* wk = (const float*)d_in[3];
    const float* wv = (const float*)d_in[4];
    const float* wo = (const float*)d_in[5];
    float* out = (float*)d_out;

    char* ws = (char*)d_ws;
    __hip_bfloat16* xb    = (__hip_bfloat16*)(ws);                 // 4096x2048 (16MB)
    __hip_bfloat16* attn  = (__hip_bfloat16*)(ws);                 // reuses xb after QKV GEMM
    __hip_bfloat16* wqkvb = (__hip_bfloat16*)(ws + 16777216ull);   // 6144x2048 (24MB)
    __hip_bfloat16* wob   = (__hip_bfloat16*)(ws + 41943040ull);   // 2048x2048 (8MB)
    __hip_bfloat16* qkv   = (__hip_bfloat16*)(ws + 50331648ull);   // 4096x6144 (48MB)
    __hip_bfloat16* vtg   = (__hip_bfloat16*)(ws + 100663296ull);  // 32x128x2048 (16MB)

    const int nx = BATCH * SEQ * DIM;
    const int nw = DIM * DIM;
    cast_kernel<<<nx / 4 / 256, 256, 0, stream>>>(x, xb, nx);
    cast_kernel<<<nw / 4 / 256, 256, 0, stream>>>(wq, wqkvb, nw);
    cast_kernel<<<nw / 4 / 256, 256, 0, stream>>>(wk, wqkvb + (size_t)DIM * DIM, nw);
    cast_kernel<<<nw / 4 / 256, 256, 0, stream>>>(wv, wqkvb + 2ull * DIM * DIM, nw);
    cast_kernel<<<nw / 4 / 256, 256, 0, stream>>>(wo, wob, nw);

    // QKV = xb @ wqkvb^T : M=4096, N=6144, K=2048
    gemm_bt<__hip_bfloat16><<<dim3(QKVN / 128, (BATCH * SEQ) / 128), 256, 0, stream>>>(
        xb, wqkvb, qkv, BATCH * SEQ, QKVN, DIM);

    rope_kernel<<<(BATCH * SEQ * NH * (HD / 2)) / 256, 256, 0, stream>>>(qkv);

    vtrans_kernel<<<dim3(SEQ / 64, DIM / 64, BATCH), 256, 0, stream>>>(qkv, vtg);

    flash_kernel<<<dim3(16, BATCH * NH), 256, 0, stream>>>(qkv, vtg, attn);

    // out = attn @ wo^T : M=4096, N=2048, K=2048 (fp32 out)
    gemm_bt<float><<<dim3(DIM / 128, (BATCH * SEQ) / 128), 256, 0, stream>>>(
        attn, wob, out, BATCH * SEQ, DIM, DIM);
}